// Round 8
// baseline (175.846 us; speedup 1.0000x reference)
//
#include <hip/hip_runtime.h>
#include <math.h>

#define L    4096
#define DI   128
#define NS   16
#define KK   6
#define CM   64    // d_model
#define NC   256   // scan chunks per direction
#define CH   16    // steps per chunk

__device__ __forceinline__ float softplus_f(float x){
    return x > 20.f ? x : __logf(1.f + __expf(x));
}
__device__ __forceinline__ float silu_f(float x){
    return x / (1.f + __expf(-x));
}

// anti-diagonal rank of pixel p, closed form
__device__ __forceinline__ int rankp(int p){
    int h = p >> 6, w = p & 63, s = h + w;
    int imin = s > 63 ? s - 63 : 0;
    int off = (s < 64) ? (s*(s+1))/2 : 4096 - ((127-s)*(128-s))/2;
    return off + (h - imin);
}

// inverse: pixel with rank r (closed form + integer fixup; no table)
__device__ __forceinline__ int invrank(int r){
    int s, i;
    if(r < 2080){
        s = (int)((sqrtf(8.f*(float)r + 1.f) - 1.f) * 0.5f);
        while(((s+1)*(s+2))/2 <= r) s++;
        while((s*(s+1))/2 > r) s--;
        i = r - (s*(s+1))/2;
    } else {
        int q = 4096 - r;                    // q in [1,2016]
        int u = (int)((sqrtf(8.f*(float)q + 1.f) - 1.f) * 0.5f);
        while((u*(u+1))/2 < q) u++;
        while(u > 1 && ((u-1)*u)/2 >= q) u--;
        s = 127 - u;
        int off = 4096 - (u*(u+1))/2;
        i = (s - 63) + (r - off);
    }
    return (i << 6) | (s - i);
}

__device__ __forceinline__ int perm_in(int k, int l){
    switch(k){
        case 0: return l;
        case 1: return ((l&63)<<6) | (l>>6);
        case 2: return (L-1) - l;
        case 3: { int m = (L-1)-l; return ((m&63)<<6) | (m>>6); }
        case 4: return invrank(l);
        default: return invrank(l) ^ 63;
    }
}

// ---------------- in_proj: 8 pixels/block, direct W_in rows (R0-proven reads) ----------------
__global__ __launch_bounds__(256) void k_inproj(const float* __restrict__ x,
                                                const float* __restrict__ W_in,
                                                float* __restrict__ xx_t,
                                                float* __restrict__ sz){
    int pb = blockIdx.x * 8;
    int o  = threadIdx.x;
    __shared__ float xr[8][CM];
    if(o < 128) ((float4*)&xr[0][0])[o] = ((const float4*)(x + (size_t)pb*CM))[o];
    float4 w[16];
    const float4* wrow = (const float4*)(W_in + (size_t)o*CM);
    #pragma unroll
    for(int q=0;q<16;q++) w[q] = wrow[q];
    __syncthreads();
    float acc[8];
    #pragma unroll
    for(int pi=0;pi<8;pi++) acc[pi] = 0.f;
    #pragma unroll
    for(int q=0;q<16;q++){
        float4 wv = w[q];
        #pragma unroll
        for(int pi=0;pi<8;pi++){
            float4 xv = *((const float4*)&xr[pi][q*4]);
            acc[pi] += wv.x*xv.x + wv.y*xv.y + wv.z*xv.z + wv.w*xv.w;
        }
    }
    #pragma unroll
    for(int pi=0;pi<8;pi++){
        int p = pb + pi;
        if(o < DI) xx_t[(size_t)p*DI + o] = acc[pi];
        else       sz[(size_t)p*DI + (o-DI)] = silu_f(acc[pi]);
    }
}

// ---------------- depthwise conv 3x3 SAME + bias + SiLU — R2-proven scalar ----------------
__global__ __launch_bounds__(256) void k_conv(const float* __restrict__ xx_t,
                                              const float* __restrict__ cw,
                                              const float* __restrict__ cb,
                                              float* __restrict__ xc_t){
    int idx = blockIdx.x*256 + threadIdx.x;   // p*DI + d
    int d = idx & 127, p = idx >> 7;
    int h = p >> 6, w = p & 63;
    float acc = cb[d];
    #pragma unroll
    for(int dh=-1; dh<=1; dh++){
        int hh = h+dh; if(hh < 0 || hh >= 64) continue;
        #pragma unroll
        for(int dw=-1; dw<=1; dw++){
            int ww = w+dw; if(ww < 0 || ww >= 64) continue;
            acc += cw[d*9 + (dh+1)*3+(dw+1)] * xx_t[(size_t)(hh*64+ww)*DI + d];
        }
    }
    xc_t[idx] = silu_f(acc);
}

// ---------------- proj + scan1 fused (R7-proven) — direct xpw, 4x5+4x4 grouping ----------------
#define XT_S 132
__global__ __launch_bounds__(256) void k_projscan(const float* __restrict__ xc_t,
                                                  const float* __restrict__ xpw,   // (K,36,DI)
                                                  const float* __restrict__ dtw,   // (K,DI,4)
                                                  const float* __restrict__ dtb,   // (K,DI)
                                                  const float* __restrict__ A_logs,// (K*DI,NS)
                                                  float* __restrict__ dts,         // (K,4,L)
                                                  float* __restrict__ BT,          // (K,L,NS)
                                                  float* __restrict__ CT,          // (K,L,NS)
                                                  float* __restrict__ apb,         // (K,NC,DI,NS)
                                                  float* __restrict__ xlb){
    int b = blockIdx.x;                 // 768 = 6*128, k-interleaved
    int k = b % KK, tile = b / KK;      // tile in [0,128)
    int l0 = tile * 32;
    int t = threadIdx.x;
    __shared__ float xt[32*XT_S];       // permuted activations (= u for the scan)
    __shared__ float Btl[32*NS];
    __shared__ float dtt[4*32];

    #pragma unroll
    for(int q=0;q<4;q++){
        int lin = q*256 + t;            // 0..1023
        int row = lin >> 5, col4 = lin & 31;
        int p = perm_in(k, l0+row);
        float4 v = ((const float4*)(xc_t + (size_t)p*DI))[col4];
        *((float4*)(xt + row*XT_S + col4*4)) = v;
    }
    __syncthreads();

    // ---- proj: 32 rows x 8 col-groups (4 groups of 5 cols + 4 groups of 4) ----
    {
        int l = t & 31, g = t >> 5;
        int cbase = (g < 4) ? 5*g : 20 + 4*(g-4);
        int cnt   = (g < 4) ? 5 : 4;
        const float* xr = xt + l*XT_S;
        float acc[5];
        #pragma unroll
        for(int j=0;j<5;j++) acc[j] = 0.f;
        const float4* wbase = (const float4*)(xpw + (size_t)k*36*DI);
        for(int dd4=0; dd4<32; dd4++){
            float4 xv = *((const float4*)(xr + dd4*4));
            #pragma unroll
            for(int j=0;j<5;j++){
                if(j < cnt){
                    float4 wv = wbase[(cbase+j)*32 + dd4];
                    acc[j] += wv.x*xv.x + wv.y*xv.y + wv.z*xv.z + wv.w*xv.w;
                }
            }
        }
        #pragma unroll
        for(int j=0;j<5;j++){
            if(j < cnt){
                int c = cbase + j;
                if(c < 4){
                    dts[((size_t)k*4 + c)*L + l0 + l] = acc[j];
                    dtt[c*32 + l] = acc[j];
                } else if(c < 20){
                    BT[((size_t)k*L + l0 + l)*NS + (c-4)] = acc[j];
                    Btl[l*NS + (c-4)] = acc[j];
                } else {
                    CT[((size_t)k*L + l0 + l)*NS + (c-20)] = acc[j];
                }
            }
        }
    }
    __syncthreads();

    // ---- scan1: two chunks in parallel; h = chunk half, d = channel ----
    int h = t >> 7, d = t & 127;
    int cc = tile*2 + h;                // chunk in [0,256)
    float4 w4 = ((const float4*)dtw)[(size_t)k*DI + d];
    float  bb = dtb[k*DI + d];
    float A[NS];
    {
        const float4* ar = (const float4*)(A_logs + ((size_t)k*DI + d)*NS);
        #pragma unroll
        for(int q=0;q<4;q++){
            float4 a4 = ar[q];
            A[q*4+0] = -__expf(a4.x); A[q*4+1] = -__expf(a4.y);
            A[q*4+2] = -__expf(a4.z); A[q*4+3] = -__expf(a4.w);
        }
    }
    float xs[NS], ap[NS];
    #pragma unroll
    for(int n=0;n<NS;n++){ xs[n] = 0.f; ap[n] = 1.f; }
    #pragma unroll
    for(int i=0;i<CH;i++){
        int l = h*CH + i;
        float u = xt[l*XT_S + d];
        float dv = bb + w4.x*dtt[l] + w4.y*dtt[32+l] + w4.z*dtt[64+l] + w4.w*dtt[96+l];
        float delta = softplus_f(dv);
        float du = delta*u;
        const float* Bi = Btl + l*NS;
        #pragma unroll
        for(int n=0;n<NS;n++){
            float da = __expf(delta*A[n]);
            xs[n] = da*xs[n] + du*Bi[n];
            ap[n] *= da;
        }
    }
    int bk = k*NC + cc;
    float* apd = apb + ((size_t)bk*DI + d)*NS;
    float* xld = xlb + ((size_t)bk*DI + d)*NS;
    #pragma unroll
    for(int q=0;q<4;q++){
        ((float4*)apd)[q] = make_float4(ap[q*4],ap[q*4+1],ap[q*4+2],ap[q*4+3]);
        ((float4*)xld)[q] = make_float4(xs[q*4],xs[q*4+1],xs[q*4+2],xs[q*4+3]);
    }
}

// ---------------- scan phase 2: combine chunks (16 segs x 16 chains, 12 waves/CU) ----------------
__global__ __launch_bounds__(256) void k_comb(float* __restrict__ apb,
                                              const float* __restrict__ xlb){
    int k    = blockIdx.x >> 7;        // 6 k's, 128 groups each
    int gidx = blockIdx.x & 127;
    int seg  = threadIdx.x >> 4;       // 0..15 (16 chunks each)
    int c    = threadIdx.x & 15;       // chain within group
    int rem  = gidx*16 + c;            // 0..2047
    size_t sb = (size_t)k*NC*2048 + (size_t)seg*16*2048 + rem;
    float a[16], xl[16];
    #pragma unroll
    for(int j=0;j<16;j++){
        a[j]  = apb[sb + (size_t)j*2048];
        xl[j] = xlb[sb + (size_t)j*2048];
    }
    float Aag = 1.f, Xag = 0.f;
    #pragma unroll
    for(int j=0;j<16;j++){ Xag = a[j]*Xag + xl[j]; Aag *= a[j]; }
    __shared__ float sA[16][17], sX[16][17];
    sA[c][seg] = Aag; sX[c][seg] = Xag;
    __syncthreads();
    if(threadIdx.x < 16){
        int cc = threadIdx.x;
        float run = 0.f;
        #pragma unroll
        for(int s=0;s<16;s++){
            float at = sA[cc][s], xt = sX[cc][s];
            sX[cc][s] = run;                 // exclusive prefix = segment ini
            run = at*run + xt;
        }
    }
    __syncthreads();
    float run = sX[c][seg];
    #pragma unroll
    for(int j=0;j<16;j++){
        apb[sb + (size_t)j*2048] = run;
        run = a[j]*run + xl[j];
    }
}

// ---------------- scan phase 3: rescan with init — R2-proven (invrank for perm) ----------------
__global__ __launch_bounds__(128) void k_scan2(const float* __restrict__ xc_t,
                                               const float* __restrict__ dts,
                                               const float* __restrict__ BT,
                                               const float* __restrict__ CT,
                                               const float* __restrict__ dtw,
                                               const float* __restrict__ dtb,
                                               const float* __restrict__ A_logs,
                                               const float* __restrict__ Dsv,
                                               const float* __restrict__ inib,  // = apb
                                               float* __restrict__ yk){         // (K,L,DI)
    int bk = blockIdx.x;
    int k = bk >> 8, cc = bk & (NC-1);
    int d = threadIdx.x;
    int l0 = cc*CH;
    __shared__ float Bt[CH*NS];
    __shared__ float Ct[CH*NS];
    __shared__ float dtt[4*CH];
    __shared__ int   pt[CH];
    if(d < 64){
        ((float4*)Bt)[d] = ((const float4*)(BT + ((size_t)k*L + l0)*NS))[d];
        int r = d>>4, i = d&15;
        dtt[d] = dts[((size_t)k*4 + r)*L + l0 + i];
    } else {
        ((float4*)Ct)[d-64] = ((const float4*)(CT + ((size_t)k*L + l0)*NS))[d-64];
    }
    if(d < CH) pt[d] = perm_in(k, l0+d);
    __syncthreads();
    float u[CH];
    #pragma unroll
    for(int i=0;i<CH;i++) u[i] = xc_t[(size_t)pt[i]*DI + d];
    float4 w4 = ((const float4*)dtw)[(size_t)k*DI + d];
    float  bb = dtb[k*DI + d];
    float  Dv = Dsv[k*DI + d];
    float A[NS];
    {
        const float4* ar = (const float4*)(A_logs + ((size_t)k*DI + d)*NS);
        #pragma unroll
        for(int q=0;q<4;q++){
            float4 a4 = ar[q];
            A[q*4+0] = -__expf(a4.x); A[q*4+1] = -__expf(a4.y);
            A[q*4+2] = -__expf(a4.z); A[q*4+3] = -__expf(a4.w);
        }
    }
    float xv[NS];
    {
        const float4* ir = (const float4*)(inib + ((size_t)bk*DI + d)*NS);
        #pragma unroll
        for(int q=0;q<4;q++){
            float4 v = ir[q];
            xv[q*4+0]=v.x; xv[q*4+1]=v.y; xv[q*4+2]=v.z; xv[q*4+3]=v.w;
        }
    }
    #pragma unroll
    for(int i=0;i<CH;i++){
        float dv = bb + w4.x*dtt[i] + w4.y*dtt[CH+i] + w4.z*dtt[2*CH+i] + w4.w*dtt[3*CH+i];
        float delta = softplus_f(dv);
        float du = delta*u[i];
        const float* Bi = Bt + i*NS;
        const float* Ci = Ct + i*NS;
        float y = 0.f;
        #pragma unroll
        for(int n=0;n<NS;n++){
            float da = __expf(delta*A[n]);
            xv[n] = da*xv[n] + du*Bi[n];
            y += xv[n]*Ci[n];
        }
        yk[((size_t)k*L + l0 + i)*DI + d] = y + u[i]*Dv;
    }
}

// ---------------- gather 6 dirs + LN + gate + out-proj — direct W_out rows (R0-proven) ----------------
__global__ __launch_bounds__(128) void k_out(const float* __restrict__ yk,
                                             const float* __restrict__ sz,
                                             const float* __restrict__ ln_g,
                                             const float* __restrict__ ln_b,
                                             const float* __restrict__ W_out, // (CM,DI)
                                             float* __restrict__ out){        // (L,CM)
    int pb = blockIdx.x*4;
    int d = threadIdx.x;
    __shared__ float ms[4][DI];
    __shared__ float red[4][2][2];
    float g = ln_g[d], bc = ln_b[d];
    float yv[4];
    #pragma unroll
    for(int pi=0;pi<4;pi++){
        int p = pb+pi;
        int tp = ((p&63)<<6) | (p>>6);
        float y;
        y  = yk[((size_t)0*L + p)*DI + d];
        y += yk[((size_t)1*L + tp)*DI + d];
        y += yk[((size_t)2*L + (L-1-p))*DI + d];
        y += yk[((size_t)3*L + (L-1-tp))*DI + d];
        y += yk[((size_t)4*L + rankp(p))*DI + d];
        y += yk[((size_t)5*L + rankp(L-1-p))*DI + d];
        yv[pi] = y;
        float s1 = y, s2 = y*y;
        #pragma unroll
        for(int m=1;m<64;m<<=1){ s1 += __shfl_xor(s1,m,64); s2 += __shfl_xor(s2,m,64); }
        if((d&63)==0){ red[pi][d>>6][0] = s1; red[pi][d>>6][1] = s2; }
    }
    __syncthreads();
    #pragma unroll
    for(int pi=0;pi<4;pi++){
        float mu  = (red[pi][0][0]+red[pi][1][0]) * (1.f/DI);
        float var = (red[pi][0][1]+red[pi][1][1]) * (1.f/DI) - mu*mu;
        float yh = (yv[pi]-mu)*rsqrtf(var+1e-5f)*g + bc;
        ms[pi][d] = yh * sz[(size_t)(pb+pi)*DI + d];
    }
    __syncthreads();
    // out-proj: wave w handles pixels w*2..w*2+1; lanes = output channel
    int o = d & 63, w = d >> 6;
    float4 wreg[32];
    const float4* wr4 = (const float4*)(W_out + (size_t)o*DI);
    #pragma unroll
    for(int q=0;q<32;q++) wreg[q] = wr4[q];
    float acc[2];
    acc[0] = 0.f; acc[1] = 0.f;
    #pragma unroll
    for(int d4=0; d4<32; d4++){
        float4 wv = wreg[d4];
        #pragma unroll
        for(int q=0;q<2;q++){
            float4 xv = *((const float4*)&ms[w*2+q][d4*4]);
            acc[q] += wv.x*xv.x + wv.y*xv.y + wv.z*xv.z + wv.w*xv.w;
        }
    }
    #pragma unroll
    for(int q=0;q<2;q++)
        out[(size_t)(pb + w*2 + q)*CM + o] = acc[q];
}

extern "C" void kernel_launch(void* const* d_in, const int* in_sizes, int n_in,
                              void* d_out, int out_size, void* d_ws, size_t ws_size,
                              hipStream_t stream) {
    const float* x      = (const float*)d_in[0];
    const float* W_in   = (const float*)d_in[1];
    const float* conv_w = (const float*)d_in[2];
    const float* conv_b = (const float*)d_in[3];
    const float* xpw    = (const float*)d_in[4];
    const float* dtw    = (const float*)d_in[5];
    const float* dtb    = (const float*)d_in[6];
    const float* A_logs = (const float*)d_in[7];
    const float* Dsv    = (const float*)d_in[8];
    const float* ln_g   = (const float*)d_in[9];
    const float* ln_b   = (const float*)d_in[10];
    const float* W_out  = (const float*)d_in[11];
    float* out = (float*)d_out;

    float* ws = (float*)d_ws;
    float* xx_t = ws;                          // L*DI
    float* sz   = xx_t + (size_t)L*DI;         // L*DI
    float* xc_t = sz   + (size_t)L*DI;         // L*DI
    float* dts  = xc_t + (size_t)L*DI;         // K*4*L
    float* BT   = dts  + (size_t)KK*4*L;       // K*L*NS
    float* CT   = BT   + (size_t)KK*L*NS;      // K*L*NS
    float* apb  = CT   + (size_t)KK*L*NS;      // K*NC*DI*NS
    float* xlb  = apb  + (size_t)KK*NC*DI*NS;  // K*NC*DI*NS
    float* yk   = xlb  + (size_t)KK*NC*DI*NS;  // K*L*DI

    k_inproj  <<<L/8, 256, 0, stream>>>(x, W_in, xx_t, sz);
    k_conv    <<<(L*DI)/256, 256, 0, stream>>>(xx_t, conv_w, conv_b, xc_t);
    k_projscan<<<KK*128, 256, 0, stream>>>(xc_t, xpw, dtw, dtb, A_logs,
                                           dts, BT, CT, apb, xlb);
    k_comb    <<<KK*128, 256, 0, stream>>>(apb, xlb);
    k_scan2   <<<KK*NC, 128, 0, stream>>>(xc_t, dts, BT, CT, dtw, dtb, A_logs, Dsv, apb, yk);
    k_out     <<<L/4, 128, 0, stream>>>(yk, sz, ln_g, ln_b, W_out, out);
}

// Round 9
// 172.182 us; speedup vs baseline: 1.0213x; 1.0213x over previous
//
#include <hip/hip_runtime.h>
#include <math.h>

#define L    4096
#define DI   128
#define NS   16
#define KK   6
#define CM   64    // d_model
#define NC   256   // scan chunks per direction
#define CH   16    // steps per chunk

__device__ __forceinline__ float softplus_f(float x){
    return x > 20.f ? x : __logf(1.f + __expf(x));
}
__device__ __forceinline__ float silu_f(float x){
    return x / (1.f + __expf(-x));
}

// anti-diagonal rank of pixel p (inverse of diag_idx), closed form
__device__ __forceinline__ int rankp(int p){
    int h = p >> 6, w = p & 63, s = h + w;
    int imin = s > 63 ? s - 63 : 0;
    int off = (s < 64) ? (s*(s+1))/2 : 4096 - ((127-s)*(128-s))/2;
    return off + (h - imin);
}

__device__ __forceinline__ int perm_in(int k, int l, const int* __restrict__ diag){
    switch(k){
        case 0: return l;
        case 1: return ((l&63)<<6) | (l>>6);
        case 2: return (L-1) - l;
        case 3: { int m = (L-1)-l; return ((m&63)<<6) | (m>>6); }
        case 4: return diag[l];
        default: return diag[l] ^ 63;
    }
}

// ---------------- init: diag table + packed weights — R7 proven ----------------
__global__ __launch_bounds__(256) void k_init(const float* __restrict__ W_in,
                                              const float* __restrict__ W_out,
                                              const float* __restrict__ conv_w,
                                              const float* __restrict__ xpw,
                                              int* __restrict__ diag_idx,
                                              float* __restrict__ WI4,
                                              float* __restrict__ WO4,
                                              float* __restrict__ cwT,
                                              float* __restrict__ PW40){
    int t = blockIdx.x*256 + threadIdx.x;   // 0..4095
    diag_idx[rankp(t)] = t;
    {
        int d4 = t >> 8, o = t & 255;
        ((float4*)WI4)[d4*256 + o] = make_float4(
            W_in[(size_t)o*CM + d4*4+0], W_in[(size_t)o*CM + d4*4+1],
            W_in[(size_t)o*CM + d4*4+2], W_in[(size_t)o*CM + d4*4+3]);
    }
    if(t < 2048){
        int d4 = t >> 6, o = t & 63;
        ((float4*)WO4)[d4*64 + o] = make_float4(
            W_out[(size_t)o*DI + d4*4+0], W_out[(size_t)o*DI + d4*4+1],
            W_out[(size_t)o*DI + d4*4+2], W_out[(size_t)o*DI + d4*4+3]);
    }
    if(t < 9*DI){
        int tap = t >> 7, d = t & 127;
        cwT[t] = conv_w[d*9 + tap];
    }
    for(int r = t; r < KK*40*32; r += 4096){
        int k = r / (40*32), rem = r % (40*32);
        int c = rem >> 5, dd4 = rem & 31;
        float4 v = make_float4(0.f, 0.f, 0.f, 0.f);
        if(c < 36) v = ((const float4*)(xpw + ((size_t)k*36 + c)*DI))[dd4];
        ((float4*)PW40)[r] = v;
    }
}

// ---------------- in_proj: 8 pixels/block, WI4 coalesced weights — R2/R7 proven ----------------
__global__ __launch_bounds__(256) void k_inproj(const float* __restrict__ x,
                                                const float* __restrict__ WI4,
                                                float* __restrict__ xx_t,
                                                float* __restrict__ sz){
    int pb = blockIdx.x * 8;
    int o  = threadIdx.x;
    __shared__ float xr[8][CM];
    if(o < 128) ((float4*)&xr[0][0])[o] = ((const float4*)(x + (size_t)pb*CM))[o];
    float4 w[16];
    const float4* W4 = (const float4*)WI4;
    #pragma unroll
    for(int q=0;q<16;q++) w[q] = W4[q*256 + o];
    __syncthreads();
    float acc[8];
    #pragma unroll
    for(int pi=0;pi<8;pi++) acc[pi] = 0.f;
    #pragma unroll
    for(int q=0;q<16;q++){
        float4 wv = w[q];
        #pragma unroll
        for(int pi=0;pi<8;pi++){
            float4 xv = *((const float4*)&xr[pi][q*4]);
            acc[pi] += wv.x*xv.x + wv.y*xv.y + wv.z*xv.z + wv.w*xv.w;
        }
    }
    #pragma unroll
    for(int pi=0;pi<8;pi++){
        int p = pb + pi;
        if(o < DI) xx_t[(size_t)p*DI + o] = acc[pi];
        else       sz[(size_t)p*DI + (o-DI)] = silu_f(acc[pi]);
    }
}

// ---------------- depthwise conv 3x3 SAME + bias + SiLU, float4 — R4/R7 proven ----------------
__global__ __launch_bounds__(256) void k_conv(const float* __restrict__ xx_t,
                                              const float* __restrict__ cwT,
                                              const float* __restrict__ cb,
                                              float* __restrict__ xc_t){
    int idx = blockIdx.x*256 + threadIdx.x;   // p*(DI/4) + d4
    int dq = (idx & 31)*4, p = idx >> 5;
    int h = p >> 6, w = p & 63;
    float4 acc = *((const float4*)(cb + dq));
    #pragma unroll
    for(int dh=-1; dh<=1; dh++){
        int hh = h+dh; if(hh < 0 || hh >= 64) continue;
        #pragma unroll
        for(int dw=-1; dw<=1; dw++){
            int ww = w+dw; if(ww < 0 || ww >= 64) continue;
            int tap = (dh+1)*3 + (dw+1);
            float4 xv = *((const float4*)(xx_t + (size_t)(hh*64+ww)*DI + dq));
            float4 wv = *((const float4*)(cwT + tap*DI + dq));
            acc.x += wv.x*xv.x; acc.y += wv.y*xv.y;
            acc.z += wv.z*xv.z; acc.w += wv.w*xv.w;
        }
    }
    *((float4*)(xc_t + (size_t)p*DI + dq)) =
        make_float4(silu_f(acc.x), silu_f(acc.y), silu_f(acc.z), silu_f(acc.w));
}

// ---------------- proj + scan1 fused v2 — R7 proven verbatim ----------------
#define XT_S 132
__global__ __launch_bounds__(256) void k_projscan(const float* __restrict__ xc_t,
                                                  const float* __restrict__ PW40,  // (K,40,DI)
                                                  const int* __restrict__ diag,
                                                  const float* __restrict__ dtw,   // (K,DI,4)
                                                  const float* __restrict__ dtb,   // (K,DI)
                                                  const float* __restrict__ A_logs,// (K*DI,NS)
                                                  float* __restrict__ dts,         // (K,4,L)
                                                  float* __restrict__ BT,          // (K,L,NS)
                                                  float* __restrict__ CT,          // (K,L,NS)
                                                  float* __restrict__ apb,         // (K,NC,DI,NS)
                                                  float* __restrict__ xlb){
    int b = blockIdx.x;                 // 768 = 6*128, k-interleaved
    int k = b % KK, tile = b / KK;      // tile in [0,128)
    int l0 = tile * 32;
    int t = threadIdx.x;
    __shared__ float xt[32*XT_S];       // permuted activations (= u for the scan)
    __shared__ float Btl[32*NS];
    __shared__ float dtt[4*32];

    #pragma unroll
    for(int q=0;q<4;q++){
        int lin = q*256 + t;            // 0..1023
        int row = lin >> 5, col4 = lin & 31;
        int p = perm_in(k, l0+row, diag);
        float4 v = ((const float4*)(xc_t + (size_t)p*DI))[col4];
        *((float4*)(xt + row*XT_S + col4*4)) = v;
    }
    __syncthreads();

    // ---- proj: 32 rows x 8 col-groups of 5 (cols 36..39 dummy) ----
    {
        int l = t & 31, g = t >> 5;
        const float* xr = xt + l*XT_S;
        float acc[5];
        #pragma unroll
        for(int j=0;j<5;j++) acc[j] = 0.f;
        const float4* wbase = (const float4*)PW40 + (size_t)k*40*32;
        for(int dd4=0; dd4<32; dd4++){
            float4 xv = *((const float4*)(xr + dd4*4));
            #pragma unroll
            for(int j=0;j<5;j++){
                float4 wv = wbase[(g*5+j)*32 + dd4];
                acc[j] += wv.x*xv.x + wv.y*xv.y + wv.z*xv.z + wv.w*xv.w;
            }
        }
        #pragma unroll
        for(int j=0;j<5;j++){
            int c = g*5 + j;
            if(c < 4){
                dts[((size_t)k*4 + c)*L + l0 + l] = acc[j];
                dtt[c*32 + l] = acc[j];
            } else if(c < 20){
                BT[((size_t)k*L + l0 + l)*NS + (c-4)] = acc[j];
                Btl[l*NS + (c-4)] = acc[j];
            } else if(c < 36){
                CT[((size_t)k*L + l0 + l)*NS + (c-20)] = acc[j];
            }
        }
    }
    __syncthreads();

    // ---- scan1: two chunks in parallel; h = chunk half, d = channel ----
    int h = t >> 7, d = t & 127;
    int cc = tile*2 + h;                // chunk in [0,256)
    float4 w4 = ((const float4*)dtw)[(size_t)k*DI + d];
    float  bb = dtb[k*DI + d];
    float A[NS];
    {
        const float4* ar = (const float4*)(A_logs + ((size_t)k*DI + d)*NS);
        #pragma unroll
        for(int q=0;q<4;q++){
            float4 a4 = ar[q];
            A[q*4+0] = -__expf(a4.x); A[q*4+1] = -__expf(a4.y);
            A[q*4+2] = -__expf(a4.z); A[q*4+3] = -__expf(a4.w);
        }
    }
    float xs[NS], ap[NS];
    #pragma unroll
    for(int n=0;n<NS;n++){ xs[n] = 0.f; ap[n] = 1.f; }
    #pragma unroll
    for(int i=0;i<CH;i++){
        int l = h*CH + i;
        float u = xt[l*XT_S + d];
        float dv = bb + w4.x*dtt[l] + w4.y*dtt[32+l] + w4.z*dtt[64+l] + w4.w*dtt[96+l];
        float delta = softplus_f(dv);
        float du = delta*u;
        const float* Bi = Btl + l*NS;
        #pragma unroll
        for(int n=0;n<NS;n++){
            float da = __expf(delta*A[n]);
            xs[n] = da*xs[n] + du*Bi[n];
            ap[n] *= da;
        }
    }
    int bk = k*NC + cc;
    float* apd = apb + ((size_t)bk*DI + d)*NS;
    float* xld = xlb + ((size_t)bk*DI + d)*NS;
    #pragma unroll
    for(int q=0;q<4;q++){
        ((float4*)apd)[q] = make_float4(ap[q*4],ap[q*4+1],ap[q*4+2],ap[q*4+3]);
        ((float4*)xld)[q] = make_float4(xs[q*4],xs[q*4+1],xs[q*4+2],xs[q*4+3]);
    }
}

// ---------------- scan phase 2: combine (16 segs x 16 chains, 12 waves/CU) — R8 proven ----------------
__global__ __launch_bounds__(256) void k_comb(float* __restrict__ apb,
                                              const float* __restrict__ xlb){
    int k    = blockIdx.x >> 7;        // 6 k's, 128 groups each
    int gidx = blockIdx.x & 127;
    int seg  = threadIdx.x >> 4;       // 0..15 (16 chunks each)
    int c    = threadIdx.x & 15;       // chain within group
    int rem  = gidx*16 + c;            // 0..2047
    size_t sb = (size_t)k*NC*2048 + (size_t)seg*16*2048 + rem;
    float a[16], xl[16];
    #pragma unroll
    for(int j=0;j<16;j++){
        a[j]  = apb[sb + (size_t)j*2048];
        xl[j] = xlb[sb + (size_t)j*2048];
    }
    float Aag = 1.f, Xag = 0.f;
    #pragma unroll
    for(int j=0;j<16;j++){ Xag = a[j]*Xag + xl[j]; Aag *= a[j]; }
    __shared__ float sA[16][17], sX[16][17];
    sA[c][seg] = Aag; sX[c][seg] = Xag;
    __syncthreads();
    if(threadIdx.x < 16){
        int cc = threadIdx.x;
        float run = 0.f;
        #pragma unroll
        for(int s=0;s<16;s++){
            float at = sA[cc][s], xt = sX[cc][s];
            sX[cc][s] = run;                 // exclusive prefix = segment ini
            run = at*run + xt;
        }
    }
    __syncthreads();
    float run = sX[c][seg];
    #pragma unroll
    for(int j=0;j<16;j++){
        apb[sb + (size_t)j*2048] = run;
        run = a[j]*run + xl[j];
    }
}

// ---------------- scan phase 3: rescan with init — R2/R7 proven verbatim ----------------
__global__ __launch_bounds__(128) void k_scan2(const float* __restrict__ xc_t,
                                               const float* __restrict__ dts,
                                               const float* __restrict__ BT,
                                               const float* __restrict__ CT,
                                               const float* __restrict__ dtw,
                                               const float* __restrict__ dtb,
                                               const float* __restrict__ A_logs,
                                               const float* __restrict__ Dsv,
                                               const int* __restrict__ diag,
                                               const float* __restrict__ inib,  // = apb
                                               float* __restrict__ yk){         // (K,L,DI)
    int bk = blockIdx.x;
    int k = bk >> 8, cc = bk & (NC-1);
    int d = threadIdx.x;
    int l0 = cc*CH;
    __shared__ float Bt[CH*NS];
    __shared__ float Ct[CH*NS];
    __shared__ float dtt[4*CH];
    __shared__ int   pt[CH];
    if(d < 64){
        ((float4*)Bt)[d] = ((const float4*)(BT + ((size_t)k*L + l0)*NS))[d];
        int r = d>>4, i = d&15;
        dtt[d] = dts[((size_t)k*4 + r)*L + l0 + i];
    } else {
        ((float4*)Ct)[d-64] = ((const float4*)(CT + ((size_t)k*L + l0)*NS))[d-64];
    }
    if(d < CH) pt[d] = perm_in(k, l0+d, diag);
    __syncthreads();
    float u[CH];
    #pragma unroll
    for(int i=0;i<CH;i++) u[i] = xc_t[(size_t)pt[i]*DI + d];
    float4 w4 = ((const float4*)dtw)[(size_t)k*DI + d];
    float  bb = dtb[k*DI + d];
    float  Dv = Dsv[k*DI + d];
    float A[NS];
    {
        const float4* ar = (const float4*)(A_logs + ((size_t)k*DI + d)*NS);
        #pragma unroll
        for(int q=0;q<4;q++){
            float4 a4 = ar[q];
            A[q*4+0] = -__expf(a4.x); A[q*4+1] = -__expf(a4.y);
            A[q*4+2] = -__expf(a4.z); A[q*4+3] = -__expf(a4.w);
        }
    }
    float xv[NS];
    {
        const float4* ir = (const float4*)(inib + ((size_t)bk*DI + d)*NS);
        #pragma unroll
        for(int q=0;q<4;q++){
            float4 v = ir[q];
            xv[q*4+0]=v.x; xv[q*4+1]=v.y; xv[q*4+2]=v.z; xv[q*4+3]=v.w;
        }
    }
    #pragma unroll
    for(int i=0;i<CH;i++){
        float dv = bb + w4.x*dtt[i] + w4.y*dtt[CH+i] + w4.z*dtt[2*CH+i] + w4.w*dtt[3*CH+i];
        float delta = softplus_f(dv);
        float du = delta*u[i];
        const float* Bi = Bt + i*NS;
        const float* Ci = Ct + i*NS;
        float y = 0.f;
        #pragma unroll
        for(int n=0;n<NS;n++){
            float da = __expf(delta*A[n]);
            xv[n] = da*xv[n] + du*Bi[n];
            y += xv[n]*Ci[n];
        }
        yk[((size_t)k*L + l0 + i)*DI + d] = y + u[i]*Dv;
    }
}

// ---------------- gather 6 dirs + LayerNorm + gate + out-proj — R2/R7 proven verbatim ----------------
__global__ __launch_bounds__(128) void k_out(const float* __restrict__ yk,
                                             const float* __restrict__ sz,
                                             const float* __restrict__ ln_g,
                                             const float* __restrict__ ln_b,
                                             const float* __restrict__ WO4,
                                             float* __restrict__ out){
    int pb = blockIdx.x*4;
    int d = threadIdx.x;
    __shared__ float ms[4][DI];
    __shared__ float red[4][2][2];
    float g = ln_g[d], bc = ln_b[d];
    float yv[4];
    #pragma unroll
    for(int pi=0;pi<4;pi++){
        int p = pb+pi;
        int tp = ((p&63)<<6) | (p>>6);
        float y;
        y  = yk[((size_t)0*L + p)*DI + d];
        y += yk[((size_t)1*L + tp)*DI + d];
        y += yk[((size_t)2*L + (L-1-p))*DI + d];
        y += yk[((size_t)3*L + (L-1-tp))*DI + d];
        y += yk[((size_t)4*L + rankp(p))*DI + d];
        y += yk[((size_t)5*L + rankp(L-1-p))*DI + d];
        yv[pi] = y;
        float s1 = y, s2 = y*y;
        #pragma unroll
        for(int m=1;m<64;m<<=1){ s1 += __shfl_xor(s1,m,64); s2 += __shfl_xor(s2,m,64); }
        if((d&63)==0){ red[pi][d>>6][0] = s1; red[pi][d>>6][1] = s2; }
    }
    __syncthreads();
    #pragma unroll
    for(int pi=0;pi<4;pi++){
        float mu  = (red[pi][0][0]+red[pi][1][0]) * (1.f/DI);
        float var = (red[pi][0][1]+red[pi][1][1]) * (1.f/DI) - mu*mu;
        float yh = (yv[pi]-mu)*rsqrtf(var+1e-5f)*g + bc;
        ms[pi][d] = yh * sz[(size_t)(pb+pi)*DI + d];
    }
    __syncthreads();
    int o = d & 63, w = d >> 6;
    const float4* W4 = (const float4*)WO4;
    float acc[2];
    acc[0] = 0.f; acc[1] = 0.f;
    #pragma unroll 8
    for(int d4=0; d4<32; d4++){
        float4 wv = W4[d4*64 + o];
        #pragma unroll
        for(int q=0;q<2;q++){
            float4 xv = *((const float4*)&ms[w*2+q][d4*4]);
            acc[q] += wv.x*xv.x + wv.y*xv.y + wv.z*xv.z + wv.w*xv.w;
        }
    }
    #pragma unroll
    for(int q=0;q<2;q++)
        out[(size_t)(pb + w*2 + q)*CM + o] = acc[q];
}

extern "C" void kernel_launch(void* const* d_in, const int* in_sizes, int n_in,
                              void* d_out, int out_size, void* d_ws, size_t ws_size,
                              hipStream_t stream) {
    const float* x      = (const float*)d_in[0];
    const float* W_in   = (const float*)d_in[1];
    const float* conv_w = (const float*)d_in[2];
    const float* conv_b = (const float*)d_in[3];
    const float* xpw    = (const float*)d_in[4];
    const float* dtw    = (const float*)d_in[5];
    const float* dtb    = (const float*)d_in[6];
    const float* A_logs = (const float*)d_in[7];
    const float* Dsv    = (const float*)d_in[8];
    const float* ln_g   = (const float*)d_in[9];
    const float* ln_b   = (const float*)d_in[10];
    const float* W_out  = (const float*)d_in[11];
    float* out = (float*)d_out;

    float* ws = (float*)d_ws;
    float* xx_t = ws;                          // L*DI
    float* sz   = xx_t + (size_t)L*DI;         // L*DI
    float* xc_t = sz   + (size_t)L*DI;         // L*DI
    float* dts  = xc_t + (size_t)L*DI;         // K*4*L
    float* BT   = dts  + (size_t)KK*4*L;       // K*L*NS
    float* CT   = BT   + (size_t)KK*L*NS;      // K*L*NS
    float* apb  = CT   + (size_t)KK*L*NS;      // K*NC*DI*NS
    float* xlb  = apb  + (size_t)KK*NC*DI*NS;  // K*NC*DI*NS
    float* yk   = xlb  + (size_t)KK*NC*DI*NS;  // K*L*DI
    int*   diag = (int*)(yk + (size_t)KK*L*DI);// L ints
    float* WI4  = (float*)(diag + L);          // 16*256*4 floats
    float* WO4  = WI4 + (size_t)16*256*4;      // 32*64*4 floats
    float* cwT  = WO4 + (size_t)32*64*4;       // 9*128 floats
    float* PW40 = cwT + (size_t)9*DI;          // K*40*128 floats

    k_init    <<<L/256, 256, 0, stream>>>(W_in, W_out, conv_w, xpw, diag, WI4, WO4, cwT, PW40);
    k_inproj  <<<L/8, 256, 0, stream>>>(x, WI4, xx_t, sz);
    k_conv    <<<(L*DI/4)/256, 256, 0, stream>>>(xx_t, cwT, conv_b, xc_t);
    k_projscan<<<KK*128, 256, 0, stream>>>(xc_t, PW40, diag, dtw, dtb, A_logs,
                                           dts, BT, CT, apb, xlb);
    k_comb    <<<KK*128, 256, 0, stream>>>(apb, xlb);
    k_scan2   <<<KK*NC, 128, 0, stream>>>(xc_t, dts, BT, CT, dtw, dtb, A_logs, Dsv, diag, apb, yk);
    k_out     <<<L/4, 128, 0, stream>>>(yk, sz, ln_g, ln_b, WO4, out);
}

// Round 10
// 165.054 us; speedup vs baseline: 1.0654x; 1.0432x over previous
//
#include <hip/hip_runtime.h>
#include <math.h>

#define L    4096
#define DI   128
#define NS   16
#define KK   6
#define CM   64    // d_model
#define NC   256   // scan chunks per direction
#define CH   16    // steps per chunk

__device__ __forceinline__ float softplus_f(float x){
    return x > 20.f ? x : __logf(1.f + __expf(x));
}
__device__ __forceinline__ float silu_f(float x){
    return x / (1.f + __expf(-x));
}

// anti-diagonal rank of pixel p (inverse of diag_idx), closed form
__device__ __forceinline__ int rankp(int p){
    int h = p >> 6, w = p & 63, s = h + w;
    int imin = s > 63 ? s - 63 : 0;
    int off = (s < 64) ? (s*(s+1))/2 : 4096 - ((127-s)*(128-s))/2;
    return off + (h - imin);
}

__device__ __forceinline__ int perm_in(int k, int l, const int* __restrict__ diag){
    switch(k){
        case 0: return l;
        case 1: return ((l&63)<<6) | (l>>6);
        case 2: return (L-1) - l;
        case 3: { int m = (L-1)-l; return ((m&63)<<6) | (m>>6); }
        case 4: return diag[l];
        default: return diag[l] ^ 63;
    }
}

// ---------------- init: diag table + packed weights ----------------
// WI4[d4*256 + o] = float4(W_in[o][4*d4..])
// WO4[d4*64  + o] = float4(W_out[o][4*d4..])
// cwT[tap*DI + d] = conv_w[d][tap]
// PW40[(k*40 + c)*32 + dd4] = float4(xpw[k][c][4*dd4..]) for c<36, else 0
__global__ __launch_bounds__(256) void k_init(const float* __restrict__ W_in,
                                              const float* __restrict__ W_out,
                                              const float* __restrict__ conv_w,
                                              const float* __restrict__ xpw,
                                              int* __restrict__ diag_idx,
                                              float* __restrict__ WI4,
                                              float* __restrict__ WO4,
                                              float* __restrict__ cwT,
                                              float* __restrict__ PW40){
    int t = blockIdx.x*256 + threadIdx.x;   // 0..4095
    diag_idx[rankp(t)] = t;
    {
        int d4 = t >> 8, o = t & 255;
        ((float4*)WI4)[d4*256 + o] = make_float4(
            W_in[(size_t)o*CM + d4*4+0], W_in[(size_t)o*CM + d4*4+1],
            W_in[(size_t)o*CM + d4*4+2], W_in[(size_t)o*CM + d4*4+3]);
    }
    if(t < 2048){
        int d4 = t >> 6, o = t & 63;
        ((float4*)WO4)[d4*64 + o] = make_float4(
            W_out[(size_t)o*DI + d4*4+0], W_out[(size_t)o*DI + d4*4+1],
            W_out[(size_t)o*DI + d4*4+2], W_out[(size_t)o*DI + d4*4+3]);
    }
    if(t < 9*DI){
        int tap = t >> 7, d = t & 127;
        cwT[t] = conv_w[d*9 + tap];
    }
    for(int r = t; r < KK*40*32; r += 4096){
        int k = r / (40*32), rem = r % (40*32);
        int c = rem >> 5, dd4 = rem & 31;
        float4 v = make_float4(0.f, 0.f, 0.f, 0.f);
        if(c < 36) v = ((const float4*)(xpw + ((size_t)k*36 + c)*DI))[dd4];
        ((float4*)PW40)[r] = v;
    }
}

// ---------------- in_proj: 8 pixels/block, weights in registers (coalesced) ----------------
__global__ __launch_bounds__(256) void k_inproj(const float* __restrict__ x,
                                                const float* __restrict__ WI4,
                                                float* __restrict__ xx_t,
                                                float* __restrict__ sz){
    int pb = blockIdx.x * 8;
    int o  = threadIdx.x;
    __shared__ float xr[8][CM];
    if(o < 128) ((float4*)&xr[0][0])[o] = ((const float4*)(x + (size_t)pb*CM))[o];
    float4 w[16];
    const float4* W4 = (const float4*)WI4;
    #pragma unroll
    for(int q=0;q<16;q++) w[q] = W4[q*256 + o];
    __syncthreads();
    float acc[8];
    #pragma unroll
    for(int pi=0;pi<8;pi++) acc[pi] = 0.f;
    #pragma unroll
    for(int q=0;q<16;q++){
        float4 wv = w[q];
        #pragma unroll
        for(int pi=0;pi<8;pi++){
            float4 xv = *((const float4*)&xr[pi][q*4]);
            acc[pi] += wv.x*xv.x + wv.y*xv.y + wv.z*xv.z + wv.w*xv.w;
        }
    }
    #pragma unroll
    for(int pi=0;pi<8;pi++){
        int p = pb + pi;
        if(o < DI) xx_t[(size_t)p*DI + o] = acc[pi];
        else       sz[(size_t)p*DI + (o-DI)] = silu_f(acc[pi]);
    }
}

// ---------------- depthwise conv 3x3 SAME + bias + SiLU, float4 over channels ----------------
__global__ __launch_bounds__(256) void k_conv(const float* __restrict__ xx_t,
                                              const float* __restrict__ cwT,
                                              const float* __restrict__ cb,
                                              float* __restrict__ xc_t){
    int idx = blockIdx.x*256 + threadIdx.x;   // p*(DI/4) + d4
    int dq = (idx & 31)*4, p = idx >> 5;
    int h = p >> 6, w = p & 63;
    float4 acc = *((const float4*)(cb + dq));
    #pragma unroll
    for(int dh=-1; dh<=1; dh++){
        int hh = h+dh; if(hh < 0 || hh >= 64) continue;
        #pragma unroll
        for(int dw=-1; dw<=1; dw++){
            int ww = w+dw; if(ww < 0 || ww >= 64) continue;
            int tap = (dh+1)*3 + (dw+1);
            float4 xv = *((const float4*)(xx_t + (size_t)(hh*64+ww)*DI + dq));
            float4 wv = *((const float4*)(cwT + tap*DI + dq));
            acc.x += wv.x*xv.x; acc.y += wv.y*xv.y;
            acc.z += wv.z*xv.z; acc.w += wv.w*xv.w;
        }
    }
    *((float4*)(xc_t + (size_t)p*DI + dq)) =
        make_float4(silu_f(acc.x), silu_f(acc.y), silu_f(acc.z), silu_f(acc.w));
}

// ---------------- proj + scan1 fused v2: 32 rows, 256 thr, parallel chunks ----------------
#define XT_S 132
__global__ __launch_bounds__(256) void k_projscan(const float* __restrict__ xc_t,
                                                  const float* __restrict__ PW40,  // (K,40,DI)
                                                  const int* __restrict__ diag,
                                                  const float* __restrict__ dtw,   // (K,DI,4)
                                                  const float* __restrict__ dtb,   // (K,DI)
                                                  const float* __restrict__ A_logs,// (K*DI,NS)
                                                  float* __restrict__ dts,         // (K,4,L)
                                                  float* __restrict__ BT,          // (K,L,NS)
                                                  float* __restrict__ CT,          // (K,L,NS)
                                                  float* __restrict__ apb,         // (K,NC,DI,NS)
                                                  float* __restrict__ xlb){
    int b = blockIdx.x;                 // 768 = 6*128, k-interleaved
    int k = b % KK, tile = b / KK;      // tile in [0,128)
    int l0 = tile * 32;
    int t = threadIdx.x;
    __shared__ float xt[32*XT_S];       // permuted activations (= u for the scan)
    __shared__ float Btl[32*NS];
    __shared__ float dtt[4*32];

    #pragma unroll
    for(int q=0;q<4;q++){
        int lin = q*256 + t;            // 0..1023
        int row = lin >> 5, col4 = lin & 31;
        int p = perm_in(k, l0+row, diag);
        float4 v = ((const float4*)(xc_t + (size_t)p*DI))[col4];
        *((float4*)(xt + row*XT_S + col4*4)) = v;
    }
    __syncthreads();

    // ---- proj: 32 rows x 8 col-groups of 5 (cols 36..39 dummy) ----
    {
        int l = t & 31, g = t >> 5;
        const float* xr = xt + l*XT_S;
        float acc[5];
        #pragma unroll
        for(int j=0;j<5;j++) acc[j] = 0.f;
        const float4* wbase = (const float4*)PW40 + (size_t)k*40*32;
        for(int dd4=0; dd4<32; dd4++){
            float4 xv = *((const float4*)(xr + dd4*4));
            #pragma unroll
            for(int j=0;j<5;j++){
                float4 wv = wbase[(g*5+j)*32 + dd4];
                acc[j] += wv.x*xv.x + wv.y*xv.y + wv.z*xv.z + wv.w*xv.w;
            }
        }
        #pragma unroll
        for(int j=0;j<5;j++){
            int c = g*5 + j;
            if(c < 4){
                dts[((size_t)k*4 + c)*L + l0 + l] = acc[j];
                dtt[c*32 + l] = acc[j];
            } else if(c < 20){
                BT[((size_t)k*L + l0 + l)*NS + (c-4)] = acc[j];
                Btl[l*NS + (c-4)] = acc[j];
            } else if(c < 36){
                CT[((size_t)k*L + l0 + l)*NS + (c-20)] = acc[j];
            }
        }
    }
    __syncthreads();

    // ---- scan1: two chunks in parallel; h = chunk half, d = channel ----
    int h = t >> 7, d = t & 127;
    int cc = tile*2 + h;                // chunk in [0,256)
    float4 w4 = ((const float4*)dtw)[(size_t)k*DI + d];
    float  bb = dtb[k*DI + d];
    float A[NS];
    {
        const float4* ar = (const float4*)(A_logs + ((size_t)k*DI + d)*NS);
        #pragma unroll
        for(int q=0;q<4;q++){
            float4 a4 = ar[q];
            A[q*4+0] = -__expf(a4.x); A[q*4+1] = -__expf(a4.y);
            A[q*4+2] = -__expf(a4.z); A[q*4+3] = -__expf(a4.w);
        }
    }
    float xs[NS], ap[NS];
    #pragma unroll
    for(int n=0;n<NS;n++){ xs[n] = 0.f; ap[n] = 1.f; }
    #pragma unroll
    for(int i=0;i<CH;i++){
        int l = h*CH + i;
        float u = xt[l*XT_S + d];
        float dv = bb + w4.x*dtt[l] + w4.y*dtt[32+l] + w4.z*dtt[64+l] + w4.w*dtt[96+l];
        float delta = softplus_f(dv);
        float du = delta*u;
        const float* Bi = Btl + l*NS;
        #pragma unroll
        for(int n=0;n<NS;n++){
            float da = __expf(delta*A[n]);
            xs[n] = da*xs[n] + du*Bi[n];
            ap[n] *= da;
        }
    }
    int bk = k*NC + cc;
    float* apd = apb + ((size_t)bk*DI + d)*NS;
    float* xld = xlb + ((size_t)bk*DI + d)*NS;
    #pragma unroll
    for(int q=0;q<4;q++){
        ((float4*)apd)[q] = make_float4(ap[q*4],ap[q*4+1],ap[q*4+2],ap[q*4+3]);
        ((float4*)xld)[q] = make_float4(xs[q*4],xs[q*4+1],xs[q*4+2],xs[q*4+3]);
    }
}

// ---------------- scan phase 2: combine chunks (8-segment parallel) — R2/R7 proven ----------------
__global__ __launch_bounds__(512) void k_comb(float* __restrict__ apb,
                                              const float* __restrict__ xlb){
    int k    = blockIdx.x >> 5;
    int gidx = blockIdx.x & 31;
    int seg  = threadIdx.x >> 6;
    int c    = threadIdx.x & 63;
    int rem  = gidx*64 + c;
    size_t sb = (size_t)k*NC*2048 + (size_t)seg*32*2048 + rem;
    float a[32], xl[32];
    #pragma unroll
    for(int j=0;j<32;j++){
        a[j]  = apb[sb + (size_t)j*2048];
        xl[j] = xlb[sb + (size_t)j*2048];
    }
    float Aag = 1.f, Xag = 0.f;
    #pragma unroll
    for(int j=0;j<32;j++){ Xag = a[j]*Xag + xl[j]; Aag *= a[j]; }
    __shared__ float sA[64][8], sX[64][8];
    sA[c][seg] = Aag; sX[c][seg] = Xag;
    __syncthreads();
    if(threadIdx.x < 64){
        float run = 0.f;
        #pragma unroll
        for(int s=0;s<8;s++){
            float at = sA[c][s], xt = sX[c][s];
            sX[c][s] = run;
            run = at*run + xt;
        }
    }
    __syncthreads();
    float run = sX[c][seg];
    #pragma unroll
    for(int j=0;j<32;j++){
        apb[sb + (size_t)j*2048] = run;
        run = a[j]*run + xl[j];
    }
}

// ---------------- scan phase 3: rescan with init — R2/R7 proven verbatim ----------------
__global__ __launch_bounds__(128) void k_scan2(const float* __restrict__ xc_t,
                                               const float* __restrict__ dts,
                                               const float* __restrict__ BT,
                                               const float* __restrict__ CT,
                                               const float* __restrict__ dtw,
                                               const float* __restrict__ dtb,
                                               const float* __restrict__ A_logs,
                                               const float* __restrict__ Dsv,
                                               const int* __restrict__ diag,
                                               const float* __restrict__ inib,  // = apb
                                               float* __restrict__ yk){         // (K,L,DI)
    int bk = blockIdx.x;
    int k = bk >> 8, cc = bk & (NC-1);
    int d = threadIdx.x;
    int l0 = cc*CH;
    __shared__ float Bt[CH*NS];
    __shared__ float Ct[CH*NS];
    __shared__ float dtt[4*CH];
    __shared__ int   pt[CH];
    if(d < 64){
        ((float4*)Bt)[d] = ((const float4*)(BT + ((size_t)k*L + l0)*NS))[d];
        int r = d>>4, i = d&15;
        dtt[d] = dts[((size_t)k*4 + r)*L + l0 + i];
    } else {
        ((float4*)Ct)[d-64] = ((const float4*)(CT + ((size_t)k*L + l0)*NS))[d-64];
    }
    if(d < CH) pt[d] = perm_in(k, l0+d, diag);
    __syncthreads();
    float u[CH];
    #pragma unroll
    for(int i=0;i<CH;i++) u[i] = xc_t[(size_t)pt[i]*DI + d];
    float4 w4 = ((const float4*)dtw)[(size_t)k*DI + d];
    float  bb = dtb[k*DI + d];
    float  Dv = Dsv[k*DI + d];
    float A[NS];
    {
        const float4* ar = (const float4*)(A_logs + ((size_t)k*DI + d)*NS);
        #pragma unroll
        for(int q=0;q<4;q++){
            float4 a4 = ar[q];
            A[q*4+0] = -__expf(a4.x); A[q*4+1] = -__expf(a4.y);
            A[q*4+2] = -__expf(a4.z); A[q*4+3] = -__expf(a4.w);
        }
    }
    float xv[NS];
    {
        const float4* ir = (const float4*)(inib + ((size_t)bk*DI + d)*NS);
        #pragma unroll
        for(int q=0;q<4;q++){
            float4 v = ir[q];
            xv[q*4+0]=v.x; xv[q*4+1]=v.y; xv[q*4+2]=v.z; xv[q*4+3]=v.w;
        }
    }
    #pragma unroll
    for(int i=0;i<CH;i++){
        float dv = bb + w4.x*dtt[i] + w4.y*dtt[CH+i] + w4.z*dtt[2*CH+i] + w4.w*dtt[3*CH+i];
        float delta = softplus_f(dv);
        float du = delta*u[i];
        const float* Bi = Bt + i*NS;
        const float* Ci = Ct + i*NS;
        float y = 0.f;
        #pragma unroll
        for(int n=0;n<NS;n++){
            float da = __expf(delta*A[n]);
            xv[n] = da*xv[n] + du*Bi[n];
            y += xv[n]*Ci[n];
        }
        yk[((size_t)k*L + l0 + i)*DI + d] = y + u[i]*Dv;
    }
}

// ---------------- gather 6 dirs + LayerNorm + gate + out-proj — R2/R7 proven verbatim ----------------
__global__ __launch_bounds__(128) void k_out(const float* __restrict__ yk,
                                             const float* __restrict__ sz,
                                             const float* __restrict__ ln_g,
                                             const float* __restrict__ ln_b,
                                             const float* __restrict__ WO4,
                                             float* __restrict__ out){
    int pb = blockIdx.x*4;
    int d = threadIdx.x;
    __shared__ float ms[4][DI];
    __shared__ float red[4][2][2];
    float g = ln_g[d], bc = ln_b[d];
    float yv[4];
    #pragma unroll
    for(int pi=0;pi<4;pi++){
        int p = pb+pi;
        int tp = ((p&63)<<6) | (p>>6);
        float y;
        y  = yk[((size_t)0*L + p)*DI + d];
        y += yk[((size_t)1*L + tp)*DI + d];
        y += yk[((size_t)2*L + (L-1-p))*DI + d];
        y += yk[((size_t)3*L + (L-1-tp))*DI + d];
        y += yk[((size_t)4*L + rankp(p))*DI + d];
        y += yk[((size_t)5*L + rankp(L-1-p))*DI + d];
        yv[pi] = y;
        float s1 = y, s2 = y*y;
        #pragma unroll
        for(int m=1;m<64;m<<=1){ s1 += __shfl_xor(s1,m,64); s2 += __shfl_xor(s2,m,64); }
        if((d&63)==0){ red[pi][d>>6][0] = s1; red[pi][d>>6][1] = s2; }
    }
    __syncthreads();
    #pragma unroll
    for(int pi=0;pi<4;pi++){
        float mu  = (red[pi][0][0]+red[pi][1][0]) * (1.f/DI);
        float var = (red[pi][0][1]+red[pi][1][1]) * (1.f/DI) - mu*mu;
        float yh = (yv[pi]-mu)*rsqrtf(var+1e-5f)*g + bc;
        ms[pi][d] = yh * sz[(size_t)(pb+pi)*DI + d];
    }
    __syncthreads();
    int o = d & 63, w = d >> 6;
    const float4* W4 = (const float4*)WO4;
    float acc[2];
    acc[0] = 0.f; acc[1] = 0.f;
    #pragma unroll 8
    for(int d4=0; d4<32; d4++){
        float4 wv = W4[d4*64 + o];
        #pragma unroll
        for(int q=0;q<2;q++){
            float4 xv = *((const float4*)&ms[w*2+q][d4*4]);
            acc[q] += wv.x*xv.x + wv.y*xv.y + wv.z*xv.z + wv.w*xv.w;
        }
    }
    #pragma unroll
    for(int q=0;q<2;q++)
        out[(size_t)(pb + w*2 + q)*CM + o] = acc[q];
}

extern "C" void kernel_launch(void* const* d_in, const int* in_sizes, int n_in,
                              void* d_out, int out_size, void* d_ws, size_t ws_size,
                              hipStream_t stream) {
    const float* x      = (const float*)d_in[0];
    const float* W_in   = (const float*)d_in[1];
    const float* conv_w = (const float*)d_in[2];
    const float* conv_b = (const float*)d_in[3];
    const float* xpw    = (const float*)d_in[4];
    const float* dtw    = (const float*)d_in[5];
    const float* dtb    = (const float*)d_in[6];
    const float* A_logs = (const float*)d_in[7];
    const float* Dsv    = (const float*)d_in[8];
    const float* ln_g   = (const float*)d_in[9];
    const float* ln_b   = (const float*)d_in[10];
    const float* W_out  = (const float*)d_in[11];
    float* out = (float*)d_out;

    float* ws = (float*)d_ws;
    float* xx_t = ws;                          // L*DI
    float* sz   = xx_t + (size_t)L*DI;         // L*DI
    float* xc_t = sz   + (size_t)L*DI;         // L*DI
    float* dts  = xc_t + (size_t)L*DI;         // K*4*L
    float* BT   = dts  + (size_t)KK*4*L;       // K*L*NS
    float* CT   = BT   + (size_t)KK*L*NS;      // K*L*NS
    float* apb  = CT   + (size_t)KK*L*NS;      // K*NC*DI*NS
    float* xlb  = apb  + (size_t)KK*NC*DI*NS;  // K*NC*DI*NS
    float* yk   = xlb  + (size_t)KK*NC*DI*NS;  // K*L*DI
    int*   diag = (int*)(yk + (size_t)KK*L*DI);// L ints
    float* WI4  = (float*)(diag + L);          // 16*256*4 floats
    float* WO4  = WI4 + (size_t)16*256*4;      // 32*64*4 floats
    float* cwT  = WO4 + (size_t)32*64*4;       // 9*128 floats
    float* PW40 = cwT + (size_t)9*DI;          // K*40*128 floats

    k_init    <<<L/256, 256, 0, stream>>>(W_in, W_out, conv_w, xpw, diag, WI4, WO4, cwT, PW40);
    k_inproj  <<<L/8, 256, 0, stream>>>(x, WI4, xx_t, sz);
    k_conv    <<<(L*DI/4)/256, 256, 0, stream>>>(xx_t, cwT, conv_b, xc_t);
    k_projscan<<<KK*128, 256, 0, stream>>>(xc_t, PW40, diag, dtw, dtb, A_logs,
                                           dts, BT, CT, apb, xlb);
    k_comb    <<<KK*32, 512, 0, stream>>>(apb, xlb);
    k_scan2   <<<KK*NC, 128, 0, stream>>>(xc_t, dts, BT, CT, dtw, dtb, A_logs, Dsv, diag, apb, yk);
    k_out     <<<L/4, 128, 0, stream>>>(yk, sz, ln_g, ln_b, WO4, out);
}